// Round 2
// baseline (8806.717 us; speedup 1.0000x reference)
//
#include <hip/hip_runtime.h>

// LiquidLayer: h_t = h + DT*(-h/tau + tanh(xW_t + h U^T + b)), T=1024 steps.
// Out = [h_final (32x1024) | states (32x1024x1024)] f32.
// Phase 1: xW GEMM (f32, tiled) written in-place into states region.
// Phase 2: ONE persistent kernel, 32 WGs; per-step grid barrier via
//          device-scope atomics + threadfence (cross-XCD safe, G16).
//          h.U^T via bf16 MFMA 16x16x32; U in VGPRs; h via global_load_lds
//          into XOR-swizzled LDS; f32 h master state lives in registers.

#define DT 0.1f
#define BB 32
#define TT 1024
#define II 512
#define HH 1024
#define NWG 32

typedef __attribute__((ext_vector_type(4))) float f32x4;
typedef __attribute__((ext_vector_type(8))) short s16x8;

__device__ __forceinline__ unsigned short f2bf(float f) {
  unsigned int u = __builtin_bit_cast(unsigned int, f);
  u += 0x7fffu + ((u >> 16) & 1u);  // RNE
  return (unsigned short)(u >> 16);
}

__device__ __forceinline__ void async16(const void* g, void* l) {
  __builtin_amdgcn_global_load_lds(
      (const __attribute__((address_space(1))) unsigned int*)g,
      (__attribute__((address_space(3))) unsigned int*)l, 16, 0, 0);
}

// ---------------- Phase 1: xW[m][n] = sum_k x[m][k] * W[n][k] (f32) ---------
#define P1_LDK 36

__global__ __launch_bounds__(256) void xw_gemm(const float* __restrict__ x,
                                               const float* __restrict__ W,
                                               float* __restrict__ out) {
  __shared__ __align__(16) float Xs[128 * P1_LDK];
  __shared__ __align__(16) float Ws_s[128 * P1_LDK];
  const int tid = threadIdx.x;
  const int m0 = blockIdx.y * 128;
  const int n0 = blockIdx.x * 128;
  const int ty = tid >> 4;
  const int tx = tid & 15;
  const int lrow = tid >> 3;
  const int lf = tid & 7;

  float acc[8][8];
#pragma unroll
  for (int i = 0; i < 8; ++i)
#pragma unroll
    for (int j = 0; j < 8; ++j) acc[i][j] = 0.0f;

  for (int kk = 0; kk < II; kk += 32) {
#pragma unroll
    for (int p = 0; p < 4; ++p) {
      int r = lrow + 32 * p;
      float4 vx = *(const float4*)&x[(m0 + r) * II + kk + 4 * lf];
      *(float4*)&Xs[r * P1_LDK + 4 * lf] = vx;
      float4 vw = *(const float4*)&W[(n0 + r) * II + kk + 4 * lf];
      *(float4*)&Ws_s[r * P1_LDK + 4 * lf] = vw;
    }
    __syncthreads();
#pragma unroll
    for (int kq = 0; kq < 32; kq += 4) {
      float4 a[8], b[8];
#pragma unroll
      for (int i = 0; i < 4; ++i) {
        a[i]     = *(const float4*)&Xs[(ty * 4 + i) * P1_LDK + kq];
        a[i + 4] = *(const float4*)&Xs[(ty * 4 + i + 64) * P1_LDK + kq];
      }
#pragma unroll
      for (int j = 0; j < 8; ++j)
        b[j] = *(const float4*)&Ws_s[(tx + 16 * j) * P1_LDK + kq];
#pragma unroll
      for (int i = 0; i < 8; ++i)
#pragma unroll
        for (int j = 0; j < 8; ++j) {
          acc[i][j] += a[i].x * b[j].x;
          acc[i][j] += a[i].y * b[j].y;
          acc[i][j] += a[i].z * b[j].z;
          acc[i][j] += a[i].w * b[j].w;
        }
    }
    __syncthreads();
  }
#pragma unroll
  for (int i = 0; i < 8; ++i) {
    int m = m0 + ty * 4 + (i < 4 ? i : 64 + i - 4);
#pragma unroll
    for (int j = 0; j < 8; ++j)
      out[m * HH + n0 + tx + 16 * j] = acc[i][j];
  }
}

// ---------------- Phase 2: persistent scan ----------------------------------
// 32 WGs x 256 thr. WG owns 32 j-rows (j0 = blk*32). Waves: (mt = m-tile 0/1,
// kh = k-half 0/1). kh1 waves dump partial D to LDS; kh0 waves reduce + run
// the epilogue and carry f32 h for their (b,j) slice in registers.
__global__ __launch_bounds__(256, 1) void liquid_scan(
    const float* __restrict__ U, const float* __restrict__ bias,
    const float* __restrict__ tau, float* __restrict__ hf,
    float* __restrict__ states, unsigned short* __restrict__ hb0,
    unsigned short* __restrict__ hb1, int* __restrict__ ctr) {
  __shared__ __align__(16) unsigned short h_s[BB * HH];  // 64 KB, swizzled
  __shared__ float red[2][2][4][64];                     // 4 KB k-half partials

  const int tid = threadIdx.x;
  const int l = tid & 63;
  const int wv = tid >> 6;  // 0..3
  const int mt = wv & 1;
  const int kh = wv >> 1;
  const int n = l & 15;     // MFMA col / A-row low bits
  const int q = l >> 4;     // 0..3
  const int j0 = blockIdx.x * 32;

  // ---- B fragments (U bf16) in registers: rows j0..j0+31, k-half kh ----
  s16x8 Bfrag[2][16];
#pragma unroll
  for (int jt = 0; jt < 2; ++jt) {
    int j = j0 + jt * 16 + n;
#pragma unroll
    for (int ks = 0; ks < 16; ++ks) {
      int kb = kh * 512 + ks * 32 + q * 8;
      float4 u0 = *(const float4*)&U[j * HH + kb];
      float4 u1 = *(const float4*)&U[j * HH + kb + 4];
      s16x8 bf;
      bf[0] = (short)f2bf(u0.x); bf[1] = (short)f2bf(u0.y);
      bf[2] = (short)f2bf(u0.z); bf[3] = (short)f2bf(u0.w);
      bf[4] = (short)f2bf(u1.x); bf[5] = (short)f2bf(u1.y);
      bf[6] = (short)f2bf(u1.z); bf[7] = (short)f2bf(u1.w);
      Bfrag[jt][ks] = bf;
    }
  }

  // ---- A-frag LDS byte addresses (swizzled): chunk(b,kc) = b*128+(kc^(b&7))
  int aaddr[16];
  const int r_a = mt * 16 + n;
#pragma unroll
  for (int ks = 0; ks < 16; ++ks) {
    int kc = (kh * 16 + ks) * 4 + q;
    aaddr[ks] = (r_a * 128 + (kc ^ (r_a & 7))) * 16;
  }

  // ---- per-lane global byte offsets for the h DMA (inverse swizzle) ----
  int goff[16];
#pragma unroll
  for (int p = 0; p < 16; ++p) {
    int C = (wv * 16 + p) * 64 + l;        // phys chunk this lane fills
    int b = C >> 7;
    int kc = (C & 127) ^ (b & 7);
    goff[p] = b * 2048 + kc * 16;
  }

  // ---- epilogue constants + f32 h master state (kh0 waves only) ----
  float invt[2], bj[2];
  long long xwoff[2][4];
  float h_own[2][4];
  float xwv[2][4];
  if (kh == 0) {
#pragma unroll
    for (int jt = 0; jt < 2; ++jt) {
      int j = j0 + jt * 16 + n;
      bj[jt] = bias[j];
      invt[jt] = 1.0f / tau[j];
#pragma unroll
      for (int rr = 0; rr < 4; ++rr) {
        int b = mt * 16 + q * 4 + rr;
        xwoff[jt][rr] = ((long long)b * TT * HH + j) * 4;
        h_own[jt][rr] = 0.0f;
        // prefetch xw for t=0
        xwv[jt][rr] = *(const float*)((const char*)states + xwoff[jt][rr]);
      }
    }
  }

#pragma unroll 1
  for (int t = 0; t < TT; ++t) {
    const unsigned short* hcur = (t & 1) ? hb1 : hb0;
    unsigned short* hnxt = (t & 1) ? hb0 : hb1;

    // stage h (64 KB) -> swizzled LDS via async DMA; global side 128B-coalesced
#pragma unroll
    for (int p = 0; p < 16; ++p)
      async16((const char*)hcur + goff[p], (char*)h_s + (wv * 16 + p) * 1024);
    __syncthreads();  // compiler emits vmcnt(0) drain before s_barrier

    f32x4 acc0 = {0.f, 0.f, 0.f, 0.f}, acc1 = {0.f, 0.f, 0.f, 0.f};
#pragma unroll
    for (int ks = 0; ks < 16; ++ks) {
      s16x8 a = *(const s16x8*)((const char*)h_s + aaddr[ks]);
      acc0 = __builtin_amdgcn_mfma_f32_16x16x32_bf16(a, Bfrag[0][ks], acc0, 0, 0, 0);
      acc1 = __builtin_amdgcn_mfma_f32_16x16x32_bf16(a, Bfrag[1][ks], acc1, 0, 0, 0);
    }

    if (kh == 1) {
#pragma unroll
      for (int rr = 0; rr < 4; ++rr) {
        red[mt][0][rr][l] = acc0[rr];
        red[mt][1][rr][l] = acc1[rr];
      }
    }
    __syncthreads();

    if (kh == 0) {
#pragma unroll
      for (int jt = 0; jt < 2; ++jt) {
#pragma unroll
        for (int rr = 0; rr < 4; ++rr) {
          float dot = (jt ? acc1[rr] : acc0[rr]) + red[mt][jt][rr][l];
          float pre = xwv[jt][rr] + dot + bj[jt];
          float act = tanhf(pre);
          float h = h_own[jt][rr];
          float hnew = h + DT * (act - invt[jt] * h);
          h_own[jt][rr] = hnew;
          int b = mt * 16 + q * 4 + rr;
          int j = j0 + jt * 16 + n;
          *(float*)((char*)states + xwoff[jt][rr] + (long long)t * (HH * 4)) = hnew;
          hnxt[b * HH + j] = f2bf(hnew);
          if (t == TT - 1) hf[b * HH + j] = hnew;
        }
      }
      if (t + 1 < TT) {  // prefetch next xw; latency hides under barrier spin
#pragma unroll
        for (int jt = 0; jt < 2; ++jt)
#pragma unroll
          for (int rr = 0; rr < 4; ++rr)
            xwv[jt][rr] = *(const float*)((const char*)states + xwoff[jt][rr] +
                                          (long long)(t + 1) * (HH * 4));
      }
    }

    if (t < TT - 1) {  // grid barrier: release h writes, arrive, spin, acquire
      __threadfence();
      __syncthreads();
      if (tid == 0) {
        __hip_atomic_fetch_add(&ctr[t], 1, __ATOMIC_RELEASE,
                               __HIP_MEMORY_SCOPE_AGENT);
        while (__hip_atomic_load(&ctr[t], __ATOMIC_ACQUIRE,
                                 __HIP_MEMORY_SCOPE_AGENT) < NWG)
          __builtin_amdgcn_s_sleep(1);
      }
      __syncthreads();
      __threadfence();
    }
  }
}

// ---------------------------------------------------------------------------
extern "C" void kernel_launch(void* const* d_in, const int* in_sizes, int n_in,
                              void* d_out, int out_size, void* d_ws, size_t ws_size,
                              hipStream_t stream) {
  const float* x    = (const float*)d_in[0];
  const float* W    = (const float*)d_in[1];
  const float* U    = (const float*)d_in[2];
  const float* bias = (const float*)d_in[3];
  const float* tau  = (const float*)d_in[4];

  float* out = (float*)d_out;
  float* hf = out;                  // [32][1024] h_final
  float* states = out + BB * HH;    // [32][1024][1024]

  unsigned short* hb0 = (unsigned short*)d_ws;       // 64 KB
  unsigned short* hb1 = hb0 + BB * HH;               // 64 KB
  int* ctr = (int*)((char*)d_ws + 2 * BB * HH * 2);  // 4 KB step counters

  hipMemsetAsync(hb0, 0, BB * HH * 2, stream);   // h0 = 0
  hipMemsetAsync(ctr, 0, TT * 4, stream);        // barrier counters

  xw_gemm<<<dim3(HH / 128, (BB * TT) / 128), 256, 0, stream>>>(x, W, states);
  liquid_scan<<<NWG, 256, 0, stream>>>(U, bias, tau, hf, states, hb0, hb1, ctr);
}